// Round 2
// baseline (58.900 us; speedup 1.0000x reference)
//
#include <hip/hip_runtime.h>
#include <hip/hip_bf16.h>
#include <float.h>

// Problem constants (from reference setup_inputs)
#define B_  4
#define C_  256
#define H_  50
#define W_  50
#define R_  300
#define PH_ 7
#define PW_ 7
#define S_  (H_ * W_)        // 2500 spatial positions
#define Q_  (PH_ * PW_)      // 49 bins per ROI

// ---------------------------------------------------------------------------
// Kernel T: transpose fm [B, C, S] -> fmT [B, S, C]  (S = H*W = 2500, C = 256)
// Classic 32x32 LDS tile, 32x8 threads, 4 elements/thread. Pad to 33 to kill
// bank conflicts. Coalesced reads along S, coalesced writes along C.
// ---------------------------------------------------------------------------
__global__ __launch_bounds__(256) void transpose_fm(
    const float* __restrict__ fm,   // [B, C, S]
    float* __restrict__ fmT)        // [B, S, C]
{
    __shared__ float tile[32][33];

    const int b  = blockIdx.z;
    const int c0 = blockIdx.y * 32;           // C tile origin (256/32 = 8 exact)
    const int s0 = blockIdx.x * 32;           // S tile origin (ceil(2500/32)=79)

    const int tx = threadIdx.x;               // 0..31
    const int ty = threadIdx.y;               // 0..7

    // load: lanes along S (coalesced)
    {
        const int s = s0 + tx;
        if (s < S_) {
            #pragma unroll
            for (int j = 0; j < 4; ++j) {
                const int c = c0 + ty + j * 8;            // always < 256
                tile[ty + j * 8][tx] = fm[((size_t)b * C_ + c) * S_ + s];
            }
        }
    }
    __syncthreads();

    // store: lanes along C (coalesced)
    {
        #pragma unroll
        for (int j = 0; j < 4; ++j) {
            const int s = s0 + ty + j * 8;
            if (s < S_) {
                const int c = c0 + tx;
                fmT[((size_t)b * S_ + s) * C_ + c] = tile[tx][ty + j * 8];
            }
        }
    }
}

// ---------------------------------------------------------------------------
// Kernel P: one block per (roi, bin). 256 threads = 256 channels.
// ROI decode is block-uniform (scalar pipe); inner loops have uniform trip
// counts (no divergence); each load is a coalesced 1 KB transaction.
// ---------------------------------------------------------------------------
__global__ __launch_bounds__(256) void roi_pool_t(
    const float* __restrict__ fmT,   // [B, H, W, C]
    const float* __restrict__ rois,  // [R, 5] = x0, y0, x1, y1, batch
    float* __restrict__ out)         // [R, C, PH, PW]
{
    const int blk = blockIdx.x;           // r * 49 + q
    const int r   = blk / Q_;
    const int q   = blk - r * Q_;
    const int ph  = q / PW_;
    const int pw  = q - ph * PW_;
    const int c   = threadIdx.x;

    // --- ROI decode (uniform across block; SPATIAL_SCALE == 1.0) ---
    const float* rp = rois + r * 5;
    const float fx0 = rp[0], fy0 = rp[1], fx1 = rp[2], fy1 = rp[3], fb = rp[4];
    const int b = (int)fb;                       // trunc, matches astype(int32)

    // jnp.round == round-half-to-even == rintf
    int x0 = (int)rintf(fx0);
    int y0 = (int)rintf(fy0);
    int x1 = (int)rintf(fx1);
    int y1 = (int)rintf(fy1);
    x0 = min(max(x0, 0), W_ - 1);
    x1 = min(max(x1, 0), W_ - 1);
    y0 = min(max(y0, 0), H_ - 1);
    y1 = min(max(y1, 0), H_ - 1);
    x1 = max(x1, x0 + 1);
    y1 = max(y1, y0 + 1);
    const int roi_w = x1 - x0;                   // >= 1
    const int roi_h = y1 - y0;                   // >= 1

    // adaptive bin: start = floor(i*len/7), end = ceil((i+1)*len/7)
    const int ws = x0 + (pw * roi_w) / PW_;
    const int we = x0 + ((pw + 1) * roi_w + PW_ - 1) / PW_;
    const int hs = y0 + (ph * roi_h) / PH_;
    const int he = y0 + ((ph + 1) * roi_h + PH_ - 1) / PH_;
    // he <= y1 <= H-1+1, we <= x1 <= W-1+1 and positions < end => in-bounds;
    // reference clip is a no-op.

    const float* base = fmT + (size_t)b * S_ * C_ + c;

    float m = -FLT_MAX;
    for (int h = hs; h < he; ++h) {
        const float* rowp = base + (size_t)(h * W_) * C_;
        for (int w = ws; w < we; ++w) {
            m = fmaxf(m, rowp[(size_t)w * C_]);
        }
    }

    out[((size_t)r * C_ + c) * Q_ + q] = m;
}

extern "C" void kernel_launch(void* const* d_in, const int* in_sizes, int n_in,
                              void* d_out, int out_size, void* d_ws, size_t ws_size,
                              hipStream_t stream)
{
    const float* fm   = (const float*)d_in[0];  // [4,256,50,50]
    const float* rois = (const float*)d_in[1];  // [300,5]
    float* out        = (float*)d_out;          // [300,256,7,7]
    float* fmT        = (float*)d_ws;           // [4,2500,256] = 10.24 MB

    // Kernel T: transpose feature maps
    {
        dim3 grid((S_ + 31) / 32, C_ / 32, B_);   // (79, 8, 4)
        dim3 block(32, 8, 1);
        transpose_fm<<<grid, block, 0, stream>>>(fm, fmT);
    }

    // Kernel P: pooled max per (roi, bin), lane = channel
    {
        const int grid = R_ * Q_;                 // 14700 blocks
        roi_pool_t<<<grid, 256, 0, stream>>>(fmT, rois, out);
    }
}

// Round 3
// 50.891 us; speedup vs baseline: 1.1574x; 1.1574x over previous
//
#include <hip/hip_runtime.h>
#include <hip/hip_bf16.h>
#include <float.h>

// Problem constants (from reference setup_inputs)
#define B_  4
#define C_  256
#define H_  50
#define W_  50
#define R_  300
#define PH_ 7
#define PW_ 7
#define S_  (H_ * W_)        // 2500 spatial positions
#define Q_  (PH_ * PW_)      // 49 bins per ROI
#define NWG_POOL (R_ * Q_)   // 14700

// ---------------------------------------------------------------------------
// XCD-bijective block swizzle (guide m204): consecutive swizzled ids stay on
// one XCD -> all 49 bins of a ROI share that XCD's L2 copy of the ROI region.
// ---------------------------------------------------------------------------
__device__ __forceinline__ int xcd_swizzle(int orig, int nwg) {
    const int NXCD = 8;
    int xcd = orig % NXCD;
    int idx = orig / NXCD;
    int q   = nwg / NXCD;
    int rem = nwg % NXCD;
    int base = (xcd < rem) ? xcd * (q + 1) : rem * (q + 1) + (xcd - rem) * q;
    return base + idx;
}

// ---------------------------------------------------------------------------
// Kernel T1: transpose fm [B, C, S] -> fmT [B, S, C].  64x64 LDS tiles.
// ---------------------------------------------------------------------------
__global__ __launch_bounds__(256) void transpose_fm(
    const float* __restrict__ fm,   // [B, C, S]
    float* __restrict__ fmT)        // [B, S, C]
{
    __shared__ float tile[64][65];

    const int b  = blockIdx.z;
    const int c0 = blockIdx.y * 64;           // 256/64 = 4 exact
    const int s0 = blockIdx.x * 64;           // ceil(2500/64) = 40

    const int tx = threadIdx.x;               // 0..63
    const int ty = threadIdx.y;               // 0..3

    // load: lanes along S (coalesced 256 B per row segment)
    {
        const int s = s0 + tx;
        if (s < S_) {
            #pragma unroll
            for (int j = 0; j < 16; ++j) {
                const int c = c0 + ty + j * 4;            // < 256 always
                tile[ty + j * 4][tx] = fm[((size_t)b * C_ + c) * S_ + s];
            }
        }
    }
    __syncthreads();

    // store: lanes along C (coalesced)
    {
        #pragma unroll
        for (int j = 0; j < 16; ++j) {
            const int s = s0 + ty + j * 4;
            if (s < S_) {
                const int c = c0 + tx;
                fmT[((size_t)b * S_ + s) * C_ + c] = tile[tx][ty + j * 4];
            }
        }
    }
}

// ---------------------------------------------------------------------------
// Shared ROI decode (block-uniform, SPATIAL_SCALE == 1.0)
// ---------------------------------------------------------------------------
__device__ __forceinline__ void roi_decode(const float* __restrict__ rois, int r,
                                           int& b, int& x0, int& y0,
                                           int& roi_w, int& roi_h)
{
    const float* rp = rois + r * 5;
    b = (int)rp[4];                          // trunc, matches astype(int32)
    // jnp.round == round-half-to-even == rintf
    x0      = (int)rintf(rp[0]);
    y0      = (int)rintf(rp[1]);
    int x1  = (int)rintf(rp[2]);
    int y1  = (int)rintf(rp[3]);
    x0 = min(max(x0, 0), W_ - 1);
    x1 = min(max(x1, 0), W_ - 1);
    y0 = min(max(y0, 0), H_ - 1);
    y1 = min(max(y1, 0), H_ - 1);
    x1 = max(x1, x0 + 1);
    y1 = max(y1, y0 + 1);
    roi_w = x1 - x0;                         // >= 1
    roi_h = y1 - y0;                         // >= 1
}

// ---------------------------------------------------------------------------
// Kernel P: block = (r,q) [swizzled], lane = channel. Coalesced 1 KB reads,
// block-exclusive contiguous 1 KB write to ws2 [R, Q, C].
// ---------------------------------------------------------------------------
__global__ __launch_bounds__(256) void roi_pool_t(
    const float* __restrict__ fmT,   // [B, S, C]
    const float* __restrict__ rois,  // [R, 5]
    float* __restrict__ ws2)         // [R, Q, C]
{
    const int wg = xcd_swizzle(blockIdx.x, NWG_POOL);
    const int r  = wg / Q_;
    const int q  = wg - r * Q_;
    const int ph = q / PW_;
    const int pw = q - ph * PW_;
    const int c  = threadIdx.x;

    int b, x0, y0, roi_w, roi_h;
    roi_decode(rois, r, b, x0, y0, roi_w, roi_h);

    // adaptive bin: start = floor(i*len/7), end = ceil((i+1)*len/7)
    const int ws = x0 + (pw * roi_w) / PW_;
    const int we = x0 + ((pw + 1) * roi_w + PW_ - 1) / PW_;
    const int hs = y0 + (ph * roi_h) / PH_;
    const int he = y0 + ((ph + 1) * roi_h + PH_ - 1) / PH_;
    // positions < end are provably in-bounds; reference clip is a no-op.

    const float* base = fmT + (size_t)b * S_ * C_ + c;

    float m = -FLT_MAX;
    for (int h = hs; h < he; ++h) {
        const float* rowp = base + (h * W_) * C_;
        for (int w = ws; w < we; ++w) {
            m = fmaxf(m, rowp[w * C_]);
        }
    }

    ws2[(size_t)wg * C_ + c] = m;            // wg = r*Q + q -> [R,Q,C]
}

// ---------------------------------------------------------------------------
// Kernel T2: per-ROI transpose ws2 [Q, C] -> out [C, Q]. Coalesced both ways;
// LDS stride 257 so the store-phase reads (bank = (q + c) % 32) don't conflict.
// ---------------------------------------------------------------------------
__global__ __launch_bounds__(256) void out_transpose(
    const float* __restrict__ ws2,   // [R, Q, C]
    float* __restrict__ out)         // [R, C, Q]
{
    __shared__ float buf[Q_ * 257];
    const int r = blockIdx.x;
    const int t = threadIdx.x;
    const size_t base = (size_t)r * (Q_ * C_);   // 12544 per ROI

    #pragma unroll
    for (int k = 0; k < Q_; ++k) {               // q = k, c = t
        buf[k * 257 + t] = ws2[base + k * C_ + t];
    }
    __syncthreads();

    #pragma unroll
    for (int k = 0; k < Q_; ++k) {
        const int e = k * 256 + t;               // 49*256 = 12544 exact
        const int c = e / Q_;
        const int q = e - c * Q_;
        out[base + e] = buf[q * 257 + c];
    }
}

// ---------------------------------------------------------------------------
// Fallback A: block per ROI, lane = channel, loop all 49 bins, write out
// directly (per-thread contiguous 49-float rows; block-exclusive 50 KB region).
// Used only if ws too small for ws2.
// ---------------------------------------------------------------------------
__global__ __launch_bounds__(256) void roi_pool_direct(
    const float* __restrict__ fmT,   // [B, S, C]
    const float* __restrict__ rois,  // [R, 5]
    float* __restrict__ out)         // [R, C, Q]
{
    const int r = blockIdx.x;
    const int c = threadIdx.x;

    int b, x0, y0, roi_w, roi_h;
    roi_decode(rois, r, b, x0, y0, roi_w, roi_h);

    const float* basep = fmT + (size_t)b * S_ * C_ + c;
    float* outp = out + ((size_t)r * C_ + c) * Q_;

    for (int ph = 0; ph < PH_; ++ph) {
        const int hs = y0 + (ph * roi_h) / PH_;
        const int he = y0 + ((ph + 1) * roi_h + PH_ - 1) / PH_;
        for (int pw = 0; pw < PW_; ++pw) {
            const int ws = x0 + (pw * roi_w) / PW_;
            const int we = x0 + ((pw + 1) * roi_w + PW_ - 1) / PW_;
            float m = -FLT_MAX;
            for (int h = hs; h < he; ++h) {
                const float* rowp = basep + (h * W_) * C_;
                for (int w = ws; w < we; ++w) {
                    m = fmaxf(m, rowp[w * C_]);
                }
            }
            outp[ph * PW_ + pw] = m;
        }
    }
}

// ---------------------------------------------------------------------------
// Fallback Z (ws < fmT bytes): round-1 thread-per-output kernel, no workspace.
// ---------------------------------------------------------------------------
__global__ __launch_bounds__(256) void roi_pool_naive(
    const float* __restrict__ fm,    // [B, C, H, W]
    const float* __restrict__ rois,
    float* __restrict__ out)
{
    const int total = R_ * C_ * Q_;
    int t = blockIdx.x * blockDim.x + threadIdx.x;
    if (t >= total) return;
    int q   = t % Q_;
    int tmp = t / Q_;
    int pw  = q % PW_;
    int ph  = q / PW_;
    int c   = tmp % C_;
    int r   = tmp / C_;

    int b, x0, y0, roi_w, roi_h;
    roi_decode(rois, r, b, x0, y0, roi_w, roi_h);

    const int ws = x0 + (pw * roi_w) / PW_;
    const int we = x0 + ((pw + 1) * roi_w + PW_ - 1) / PW_;
    const int hs = y0 + (ph * roi_h) / PH_;
    const int he = y0 + ((ph + 1) * roi_h + PH_ - 1) / PH_;

    const float* p = fm + ((size_t)(b * C_ + c)) * S_;
    float m = -FLT_MAX;
    for (int h = hs; h < he; ++h)
        for (int w = ws; w < we; ++w)
            m = fmaxf(m, p[h * W_ + w]);
    out[t] = m;
}

extern "C" void kernel_launch(void* const* d_in, const int* in_sizes, int n_in,
                              void* d_out, int out_size, void* d_ws, size_t ws_size,
                              hipStream_t stream)
{
    const float* fm   = (const float*)d_in[0];  // [4,256,50,50]
    const float* rois = (const float*)d_in[1];  // [300,5]
    float* out        = (float*)d_out;          // [300,256,7,7]

    const size_t FMT_BYTES = (size_t)B_ * S_ * C_ * sizeof(float);   // 10.24 MB
    const size_t WS2_BYTES = (size_t)R_ * Q_ * C_ * sizeof(float);   // 15.05 MB

    if (ws_size >= FMT_BYTES) {
        float* fmT = (float*)d_ws;
        {
            dim3 grid((S_ + 63) / 64, C_ / 64, B_);   // (40, 4, 4)
            dim3 block(64, 4, 1);
            transpose_fm<<<grid, block, 0, stream>>>(fm, fmT);
        }
        if (ws_size >= FMT_BYTES + WS2_BYTES) {
            float* ws2 = (float*)((char*)d_ws + FMT_BYTES);
            roi_pool_t<<<NWG_POOL, 256, 0, stream>>>(fmT, rois, ws2);
            out_transpose<<<R_, 256, 0, stream>>>(ws2, out);
        } else {
            roi_pool_direct<<<R_, 256, 0, stream>>>(fmT, rois, out);
        }
    } else {
        const int total = R_ * C_ * Q_;
        roi_pool_naive<<<(total + 255) / 256, 256, 0, stream>>>(fm, rois, out);
    }
}